// Round 6
// baseline (283.639 us; speedup 1.0000x reference)
//
#include <hip/hip_runtime.h>

#define NIN 32
#define NU  128
#define RPB 4            // batch rows per block
#define NQ  4            // i-range quarters (threads per j)
#define UNFOLDS 6
#define LOG2E 1.44269504088896340736f
#define TBL_N 4096       // sigmoid table entries over t in [-16, 16)
#define TBL_SCALE 128.0f // entries per unit t
#define TBL_OFF 2048.5f  // center offset + 0.5 for round-to-nearest via trunc

typedef float float4v __attribute__((ext_vector_type(4)));

#define SPN (NIN * NU)   // 4096 sensory synapses
#define RPN (NU * NU)    // 16384 recurrent synapses

// ---- prologue: pack (a, b, We, Wv) per synapse ----
// sigmoid(sigma*(v-mu)) = 1/(1+2^t), t = s2*v + sm2, s2 = -log2e*sigma.
// Table index = trunc(TBL_SCALE*t + TBL_OFF), so fold scale/offset here:
//   a = TBL_SCALE*s2,  b = TBL_SCALE*sm2 + TBL_OFF
__global__ void pack_params(const float* __restrict__ mu,
                            const float* __restrict__ sig,
                            const float* __restrict__ W,
                            const float* __restrict__ erev,
                            float4v* __restrict__ out, int n) {
    int idx = blockIdx.x * blockDim.x + threadIdx.x;
    if (idx < n) {
        float sg = sig[idx];
        float s2 = -LOG2E * sg;
        float sm2 = -s2 * mu[idx];
        float Wv = W[idx];
        float We = Wv * erev[idx];
        out[idx] = (float4v){TBL_SCALE * s2, TBL_SCALE * sm2 + TBL_OFF, We, Wv};
    }
}

// Table-lookup sigmoid eval: 1 fma (addr) + clamp + cvt + ds gather + 2 fma.
#define EVAL_TBL(p, v, n_, d_)                                         \
    {                                                                  \
        float af = __builtin_fmaf((p).x, (v), (p).y);                  \
        af = fminf(fmaxf(af, 0.0f), (float)(TBL_N - 1));               \
        float s = tbl[(int)af];                                        \
        (n_) = __builtin_fmaf((p).z, s, (n_));                         \
        (d_) = __builtin_fmaf((p).w, s, (d_));                         \
    }

// block = 512 threads: j = tid&127 (unit), q = tid>>7 (i-quarter, wave-uniform).
// 4 batch rows per block; thread (j,q) accumulates num/den partials over its
// i-quarter for all 4 rows, partials reduced via LDS each unfold; thread
// (j,q) owns the v-update for row q. Sigmoid via 4096-entry LDS table.
__global__ __launch_bounds__(512, 8)
void wormnet_main(const float* __restrict__ inputs,   // [B,32]
                  const float* __restrict__ state,    // [B,128]
                  const float4v* __restrict__ sp,     // [32*128] packed
                  const float4v* __restrict__ rp,     // [128*128] packed
                  const float* __restrict__ vleak,
                  const float* __restrict__ gleak,
                  const float* __restrict__ cm_t,
                  const float* __restrict__ in_w, const float* __restrict__ in_b,
                  const float* __restrict__ out_w, const float* __restrict__ out_b,
                  float* __restrict__ out_y,          // [B]
                  float* __restrict__ out_v)          // [B,128]
{
    __shared__ __align__(16) float tbl[TBL_N];        // sigmoid table   16 KB
    __shared__ __align__(16) float xs[NIN * RPB];     // xs[i*4 + r]    0.5 KB
    __shared__ __align__(16) float vs[NU * RPB];      // vs[i*4 + r]      2 KB
    __shared__ float rn[RPB][NQ][NU];                 // num partials     8 KB
    __shared__ float rd[RPB][NQ][NU];                 // den partials     8 KB

    const int tid  = threadIdx.x;
    const int j    = tid & (NU - 1);
    const int q    = tid >> 7;            // 0..3, wave-uniform
    const int base = blockIdx.x * RPB;

    // build sigmoid table: s(t_k), t_k = (k - 2048)/128
    #pragma unroll
    for (int k = tid; k < TBL_N; k += 512) {
        float t = (float)(k - TBL_N / 2) * (1.0f / TBL_SCALE);
        tbl[k] = __builtin_amdgcn_rcpf(1.0f + __builtin_amdgcn_exp2f(t));
    }

    // stage x = inputs*in_w + in_b (128 values; first 128 threads)
    if (tid < NIN * RPB) {
        int i = tid & (NIN - 1);
        int r = tid >> 5;
        xs[i * RPB + r] = inputs[(base + r) * NIN + i] * in_w[i] + in_b[i];
    }
    // stage initial v (512 values, 1 per thread: this thread's update row q)
    float vold = state[(base + q) * NU + j];
    vs[j * RPB + q] = vold;
    __syncthreads();

    // ---- sensory partial sums over i-quarter [q*8, q*8+8), all 4 rows ----
    float numS[RPB], denS[RPB];
    #pragma unroll
    for (int r = 0; r < RPB; ++r) { numS[r] = 0.0f; denS[r] = 0.0f; }
    {
        const float4v* pp = sp + q * (NIN / NQ) * NU + j;
        #pragma unroll 4
        for (int ii = 0; ii < NIN / NQ; ++ii) {
            const int i = q * (NIN / NQ) + ii;
            float4v p = pp[0]; pp += NU;
            float4v xv = *(const float4v*)&xs[i * RPB];
            #pragma unroll
            for (int r = 0; r < RPB; ++r) {
                EVAL_TBL(p, xv[r], numS[r], denS[r]);
            }
        }
    }

    // per-unit constants
    const float cm = cm_t[j];
    const float gl = gleak[j];
    const float glvl = gl * vleak[j];
    const float cg = cm + gl;

    // ---- 6 semi-implicit unfolds ----
    for (int u = 0; u < UNFOLDS; ++u) {
        float num[RPB], den[RPB];
        #pragma unroll
        for (int r = 0; r < RPB; ++r) { num[r] = numS[r]; den[r] = denS[r]; }

        const float4v* pp = rp + q * (NU / NQ) * NU + j;
        #pragma unroll 4
        for (int ii = 0; ii < NU / NQ; ++ii) {
            const int i = q * (NU / NQ) + ii;
            float4v p = pp[0]; pp += NU;
            float4v vv = *(const float4v*)&vs[i * RPB];
            #pragma unroll
            for (int r = 0; r < RPB; ++r) {
                EVAL_TBL(p, vv[r], num[r], den[r]);
            }
        }

        // publish partials (coalesced over j, conflict-free)
        #pragma unroll
        for (int r = 0; r < RPB; ++r) {
            rn[r][q][j] = num[r];
            rd[r][q][j] = den[r];
        }
        __syncthreads();

        // update this thread's row q
        {
            float tn = (rn[q][0][j] + rn[q][1][j]) + (rn[q][2][j] + rn[q][3][j]);
            float td = (rd[q][0][j] + rd[q][1][j]) + (rd[q][2][j] + rd[q][3][j]);
            float vn = (__builtin_fmaf(cm, vold, glvl) + tn)
                       * __builtin_amdgcn_rcpf(cg + td);
            vold = vn;
            vs[j * RPB + q] = vn;
        }
        __syncthreads();
    }

    // ---- epilogue: thread (j,q) writes its row (coalesced over j) ----
    out_v[(base + q) * NU + j] = vold;
    if (j == 0) {
        out_y[base + q] = __builtin_fmaf(vold, out_w[0], out_b[0]);
    }
}

extern "C" void kernel_launch(void* const* d_in, const int* in_sizes, int n_in,
                              void* d_out, int out_size, void* d_ws, size_t ws_size,
                              hipStream_t stream) {
    const float* inputs  = (const float*)d_in[0];
    const float* state   = (const float*)d_in[1];
    const float* smu     = (const float*)d_in[2];
    const float* ssig    = (const float*)d_in[3];
    const float* sW      = (const float*)d_in[4];
    const float* serev   = (const float*)d_in[5];
    const float* rmu     = (const float*)d_in[6];
    const float* rsig    = (const float*)d_in[7];
    const float* rW      = (const float*)d_in[8];
    const float* rerev   = (const float*)d_in[9];
    const float* vleak   = (const float*)d_in[10];
    const float* gleak   = (const float*)d_in[11];
    const float* cm_t    = (const float*)d_in[12];
    const float* in_w    = (const float*)d_in[13];
    const float* in_b    = (const float*)d_in[14];
    const float* out_w   = (const float*)d_in[15];
    const float* out_b   = (const float*)d_in[16];

    const int batch = in_sizes[1] / NU;        // 8192
    float* out_y = (float*)d_out;              // [batch]
    float* out_v = (float*)d_out + batch;      // [batch,128]

    float4v* sp = (float4v*)d_ws;
    float4v* rp = sp + SPN;

    hipLaunchKernelGGL(pack_params, dim3((SPN + 255) / 256), dim3(256), 0, stream,
                       smu, ssig, sW, serev, sp, SPN);
    hipLaunchKernelGGL(pack_params, dim3((RPN + 255) / 256), dim3(256), 0, stream,
                       rmu, rsig, rW, rerev, rp, RPN);

    dim3 grid(batch / RPB), block(NU * NQ);    // 2048 x 512
    hipLaunchKernelGGL(wormnet_main, grid, block, 0, stream,
                       inputs, state, sp, rp,
                       vleak, gleak, cm_t, in_w, in_b, out_w, out_b,
                       out_y, out_v);
}

// Round 7
// 278.838 us; speedup vs baseline: 1.0172x; 1.0172x over previous
//
#include <hip/hip_runtime.h>

#define NIN 32
#define NU  128
#define RPB 4            // batch rows per block
#define NQ  4            // i-range quarters (threads per j)
#define UNFOLDS 6
#define LOG2E 1.44269504088896340736f
#define TBL_N 4096       // sigmoid table entries over t in [-16, 16)
#define TBL_SCALE 128.0f // entries per unit t
#define TBL_OFF 2048.5f  // center offset + 0.5 for round-to-nearest via trunc

typedef float float4v __attribute__((ext_vector_type(4)));

#define SPN (NIN * NU)   // 4096 sensory synapses
#define RPN (NU * NU)    // 16384 recurrent synapses

// ---- prologue: pack (s2, sm2, We, Wv) per synapse ----
// sigmoid(sigma*(v-mu)) = 1/(1+2^t), t = s2*v + sm2, s2 = -log2e*sigma
__global__ void pack_params(const float* __restrict__ mu,
                            const float* __restrict__ sig,
                            const float* __restrict__ W,
                            const float* __restrict__ erev,
                            float4v* __restrict__ out, int n) {
    int idx = blockIdx.x * blockDim.x + threadIdx.x;
    if (idx < n) {
        float sg = sig[idx];
        float s2 = -LOG2E * sg;
        float sm2 = -s2 * mu[idx];
        float Wv = W[idx];
        float We = Wv * erev[idx];
        out[idx] = (float4v){s2, sm2, We, Wv};
    }
}

// HYBRID eval of one synapse (param p) against 4 values vv[0..3]:
//   rows 0,1 -> exact exp2 path with pair-shared rcp   (issue pipe / trans)
//   rows 2,3 -> LDS sigmoid table gather               (LDS pipe)
// axp/bxp are p.x,p.y pre-scaled to table-index space (computed once per i).
#define EVAL_HYBRID(p, axp, bxp, vv, num, den)                                 \
    {                                                                          \
        /* exp2 pair: rows 0,1 */                                              \
        float e0 = __builtin_amdgcn_exp2f(__builtin_fmaf((p).x, (vv)[0], (p).y)); \
        float e1 = __builtin_amdgcn_exp2f(__builtin_fmaf((p).x, (vv)[1], (p).y)); \
        float a1 = 1.0f + e1;                                                  \
        float P  = __builtin_fmaf(e0, a1, a1);                                 \
        float rq = __builtin_amdgcn_rcpf(P);                                   \
        float s0 = rq * a1;                                                    \
        float s1 = __builtin_fmaf(rq, e0, rq);                                 \
        (num)[0] = __builtin_fmaf((p).z, s0, (num)[0]);                        \
        (den)[0] = __builtin_fmaf((p).w, s0, (den)[0]);                        \
        (num)[1] = __builtin_fmaf((p).z, s1, (num)[1]);                        \
        (den)[1] = __builtin_fmaf((p).w, s1, (den)[1]);                        \
        /* table gathers: rows 2,3 */                                          \
        float af2 = __builtin_fmaf((axp), (vv)[2], (bxp));                     \
        float af3 = __builtin_fmaf((axp), (vv)[3], (bxp));                     \
        af2 = fminf(fmaxf(af2, 0.0f), (float)(TBL_N - 1));                     \
        af3 = fminf(fmaxf(af3, 0.0f), (float)(TBL_N - 1));                     \
        float st2 = tbl[(int)af2];                                             \
        float st3 = tbl[(int)af3];                                             \
        (num)[2] = __builtin_fmaf((p).z, st2, (num)[2]);                       \
        (den)[2] = __builtin_fmaf((p).w, st2, (den)[2]);                       \
        (num)[3] = __builtin_fmaf((p).z, st3, (num)[3]);                       \
        (den)[3] = __builtin_fmaf((p).w, st3, (den)[3]);                       \
    }

// block = 512 threads: j = tid&127 (unit), q = tid>>7 (i-quarter, wave-uniform).
// 4 batch rows per block; thread (j,q) accumulates num/den partials over its
// i-quarter for all 4 rows (2 via exp2, 2 via LDS table -> pipes balanced),
// partials reduced via LDS each unfold; thread (j,q) owns row q's v-update.
__global__ __launch_bounds__(512, 8)
void wormnet_main(const float* __restrict__ inputs,   // [B,32]
                  const float* __restrict__ state,    // [B,128]
                  const float4v* __restrict__ sp,     // [32*128] packed
                  const float4v* __restrict__ rp,     // [128*128] packed
                  const float* __restrict__ vleak,
                  const float* __restrict__ gleak,
                  const float* __restrict__ cm_t,
                  const float* __restrict__ in_w, const float* __restrict__ in_b,
                  const float* __restrict__ out_w, const float* __restrict__ out_b,
                  float* __restrict__ out_y,          // [B]
                  float* __restrict__ out_v)          // [B,128]
{
    __shared__ __align__(16) float tbl[TBL_N];        // sigmoid table   16 KB
    __shared__ __align__(16) float xs[NIN * RPB];     // xs[i*4 + r]    0.5 KB
    __shared__ __align__(16) float vs[NU * RPB];      // vs[i*4 + r]      2 KB
    __shared__ float rn[RPB][NQ][NU];                 // num partials     8 KB
    __shared__ float rd[RPB][NQ][NU];                 // den partials     8 KB

    const int tid  = threadIdx.x;
    const int j    = tid & (NU - 1);
    const int q    = tid >> 7;            // 0..3, wave-uniform
    const int base = blockIdx.x * RPB;

    // build sigmoid table: s(t_k) = 1/(1+2^t), t_k = (k - 2048)/128
    #pragma unroll
    for (int k = tid; k < TBL_N; k += 512) {
        float t = (float)(k - TBL_N / 2) * (1.0f / TBL_SCALE);
        tbl[k] = __builtin_amdgcn_rcpf(1.0f + __builtin_amdgcn_exp2f(t));
    }

    // stage x = inputs*in_w + in_b (128 values; first 128 threads)
    if (tid < NIN * RPB) {
        int i = tid & (NIN - 1);
        int r = tid >> 5;
        xs[i * RPB + r] = inputs[(base + r) * NIN + i] * in_w[i] + in_b[i];
    }
    // stage initial v (512 values, 1 per thread: this thread's update row q)
    float vold = state[(base + q) * NU + j];
    vs[j * RPB + q] = vold;
    __syncthreads();

    // ---- sensory partial sums over i-quarter [q*8, q*8+8), all 4 rows ----
    float numS[RPB], denS[RPB];
    #pragma unroll
    for (int r = 0; r < RPB; ++r) { numS[r] = 0.0f; denS[r] = 0.0f; }
    {
        const float4v* pp = sp + q * (NIN / NQ) * NU + j;
        #pragma unroll 4
        for (int ii = 0; ii < NIN / NQ; ++ii) {
            const int i = q * (NIN / NQ) + ii;
            float4v p = pp[0]; pp += NU;
            float axp = p.x * TBL_SCALE;
            float bxp = __builtin_fmaf(p.y, TBL_SCALE, TBL_OFF);
            float4v xv = *(const float4v*)&xs[i * RPB];
            EVAL_HYBRID(p, axp, bxp, xv, numS, denS);
        }
    }

    // per-unit constants
    const float cm = cm_t[j];
    const float gl = gleak[j];
    const float glvl = gl * vleak[j];
    const float cg = cm + gl;

    // ---- 6 semi-implicit unfolds ----
    for (int u = 0; u < UNFOLDS; ++u) {
        float num[RPB], den[RPB];
        #pragma unroll
        for (int r = 0; r < RPB; ++r) { num[r] = numS[r]; den[r] = denS[r]; }

        const float4v* pp = rp + q * (NU / NQ) * NU + j;
        #pragma unroll 4
        for (int ii = 0; ii < NU / NQ; ++ii) {
            const int i = q * (NU / NQ) + ii;
            float4v p = pp[0]; pp += NU;
            float axp = p.x * TBL_SCALE;
            float bxp = __builtin_fmaf(p.y, TBL_SCALE, TBL_OFF);
            float4v vv = *(const float4v*)&vs[i * RPB];
            EVAL_HYBRID(p, axp, bxp, vv, num, den);
        }

        // publish partials (coalesced over j, conflict-free)
        #pragma unroll
        for (int r = 0; r < RPB; ++r) {
            rn[r][q][j] = num[r];
            rd[r][q][j] = den[r];
        }
        __syncthreads();

        // update this thread's row q
        {
            float tn = (rn[q][0][j] + rn[q][1][j]) + (rn[q][2][j] + rn[q][3][j]);
            float td = (rd[q][0][j] + rd[q][1][j]) + (rd[q][2][j] + rd[q][3][j]);
            float vn = (__builtin_fmaf(cm, vold, glvl) + tn)
                       * __builtin_amdgcn_rcpf(cg + td);
            vold = vn;
            vs[j * RPB + q] = vn;
        }
        __syncthreads();
    }

    // ---- epilogue: thread (j,q) writes its row (coalesced over j) ----
    out_v[(base + q) * NU + j] = vold;
    if (j == 0) {
        out_y[base + q] = __builtin_fmaf(vold, out_w[0], out_b[0]);
    }
}

extern "C" void kernel_launch(void* const* d_in, const int* in_sizes, int n_in,
                              void* d_out, int out_size, void* d_ws, size_t ws_size,
                              hipStream_t stream) {
    const float* inputs  = (const float*)d_in[0];
    const float* state   = (const float*)d_in[1];
    const float* smu     = (const float*)d_in[2];
    const float* ssig    = (const float*)d_in[3];
    const float* sW      = (const float*)d_in[4];
    const float* serev   = (const float*)d_in[5];
    const float* rmu     = (const float*)d_in[6];
    const float* rsig    = (const float*)d_in[7];
    const float* rW      = (const float*)d_in[8];
    const float* rerev   = (const float*)d_in[9];
    const float* vleak   = (const float*)d_in[10];
    const float* gleak   = (const float*)d_in[11];
    const float* cm_t    = (const float*)d_in[12];
    const float* in_w    = (const float*)d_in[13];
    const float* in_b    = (const float*)d_in[14];
    const float* out_w   = (const float*)d_in[15];
    const float* out_b   = (const float*)d_in[16];

    const int batch = in_sizes[1] / NU;        // 8192
    float* out_y = (float*)d_out;              // [batch]
    float* out_v = (float*)d_out + batch;      // [batch,128]

    float4v* sp = (float4v*)d_ws;
    float4v* rp = sp + SPN;

    hipLaunchKernelGGL(pack_params, dim3((SPN + 255) / 256), dim3(256), 0, stream,
                       smu, ssig, sW, serev, sp, SPN);
    hipLaunchKernelGGL(pack_params, dim3((RPN + 255) / 256), dim3(256), 0, stream,
                       rmu, rsig, rW, rerev, rp, RPN);

    dim3 grid(batch / RPB), block(NU * NQ);    // 2048 x 512
    hipLaunchKernelGGL(wormnet_main, grid, block, 0, stream,
                       inputs, state, sp, rp,
                       vleak, gleak, cm_t, in_w, in_b, out_w, out_b,
                       out_y, out_v);
}

// Round 8
// 266.486 us; speedup vs baseline: 1.0644x; 1.0464x over previous
//
#include <hip/hip_runtime.h>

#define NIN 32
#define NU  128
#define RPB 4            // batch rows per block
#define NQ  4            // i-range quarters (threads per j)
#define UNFOLDS 6
#define LOG2E 1.44269504088896340736f
#define TBL_N 4096       // sigmoid table entries over t in [-16, 16)
#define TBL_SCALE 128.0f // entries per unit t
#define TBL_OFF 2048.5f  // center offset + 0.5 for round-to-nearest via trunc

typedef float float4v __attribute__((ext_vector_type(4)));

#define SPN (NIN * NU)   // 4096 sensory synapses
#define RPN (NU * NU)    // 16384 recurrent synapses

// i-range split per q: q0,q1 -> exp2 method; q2,q3 -> table method.
// Recurrent: 18/18/46/46 (f_table = 0.72). Sensory: 4/4/12/12 (0.75).
__device__ __constant__ int RLOC[5] = {0, 18, 36, 82, 128};
__device__ __constant__ int SLOC[5] = {0, 4, 8, 20, 32};

// ---- prologue: pack params in BOTH spaces ----
// exp2 space:  (s2, sm2, We, Wv), t = s2*v + sm2, sigmoid = 1/(1+2^t)
// table space: (axp, bxp, We, Wv), idx = trunc(axp*v + bxp)
__global__ void pack_params(const float* __restrict__ mu,
                            const float* __restrict__ sig,
                            const float* __restrict__ W,
                            const float* __restrict__ erev,
                            float4v* __restrict__ out_e,
                            float4v* __restrict__ out_t, int n) {
    int idx = blockIdx.x * blockDim.x + threadIdx.x;
    if (idx < n) {
        float sg = sig[idx];
        float s2 = -LOG2E * sg;
        float sm2 = -s2 * mu[idx];
        float Wv = W[idx];
        float We = Wv * erev[idx];
        out_e[idx] = (float4v){s2, sm2, We, Wv};
        out_t[idx] = (float4v){TBL_SCALE * s2,
                               __builtin_fmaf(TBL_SCALE, sm2, TBL_OFF), We, Wv};
    }
}

// exp2 pair (rows r0,r1), pair-shared rcp:
#define EVAL_PAIR(p, v0, v1, n0, d0, n1, d1)                                   \
    {                                                                          \
        float e0 = __builtin_amdgcn_exp2f(__builtin_fmaf((p).x, (v0), (p).y)); \
        float e1 = __builtin_amdgcn_exp2f(__builtin_fmaf((p).x, (v1), (p).y)); \
        float a1 = 1.0f + e1;                                                  \
        float P  = __builtin_fmaf(e0, a1, a1);                                 \
        float rq = __builtin_amdgcn_rcpf(P);                                   \
        float s0 = rq * a1;                                                    \
        float s1 = __builtin_fmaf(rq, e0, rq);                                 \
        (n0) = __builtin_fmaf((p).z, s0, (n0));                                \
        (d0) = __builtin_fmaf((p).w, s0, (d0));                                \
        (n1) = __builtin_fmaf((p).z, s1, (n1));                                \
        (d1) = __builtin_fmaf((p).w, s1, (d1));                                \
    }

// table eval: fma (addr) + fmed3 clamp + cvt + gather + 2 accum fma
#define EVAL_TBL(p, v, n_, d_)                                                 \
    {                                                                          \
        float af = __builtin_fmaf((p).x, (v), (p).y);                          \
        af = __builtin_amdgcn_fmed3f(af, 0.0f, (float)(TBL_N - 1));            \
        float s = tbl[(unsigned)af];                                           \
        (n_) = __builtin_fmaf((p).z, s, (n_));                                 \
        (d_) = __builtin_fmaf((p).w, s, (d_));                                 \
    }

// block = 512 threads: j = tid&127 (unit), q = tid>>7 (wave-uniform).
// q selects BOTH the i-range and the sigmoid method (method-pure waves):
// q0,q1 exact exp2 (28% of evals, issue pipe); q2,q3 LDS table (72%, LDS pipe).
// 4 batch rows per block; partials reduced via LDS each unfold; thread (j,q)
// owns row q's v-update.
__global__ __launch_bounds__(512, 8)
void wormnet_main(const float* __restrict__ inputs,   // [B,32]
                  const float* __restrict__ state,    // [B,128]
                  const float4v* __restrict__ spe, const float4v* __restrict__ spt,
                  const float4v* __restrict__ rpe, const float4v* __restrict__ rpt,
                  const float* __restrict__ vleak,
                  const float* __restrict__ gleak,
                  const float* __restrict__ cm_t,
                  const float* __restrict__ in_w, const float* __restrict__ in_b,
                  const float* __restrict__ out_w, const float* __restrict__ out_b,
                  float* __restrict__ out_y,          // [B]
                  float* __restrict__ out_v)          // [B,128]
{
    __shared__ __align__(16) float tbl[TBL_N];        // sigmoid table   16 KB
    __shared__ __align__(16) float xs[NIN * RPB];     // xs[i*4 + r]    0.5 KB
    __shared__ __align__(16) float vs[NU * RPB];      // vs[i*4 + r]      2 KB
    __shared__ float rn[RPB][NQ][NU];                 // num partials     8 KB
    __shared__ float rd[RPB][NQ][NU];                 // den partials     8 KB

    const int tid  = threadIdx.x;
    const int j    = tid & (NU - 1);
    const int q    = tid >> 7;            // 0..3, wave-uniform
    const int base = blockIdx.x * RPB;

    // build sigmoid table: s(t_k) = 1/(1+2^t), t_k = (k - 2048)/128
    #pragma unroll
    for (int k = tid; k < TBL_N; k += 512) {
        float t = (float)(k - TBL_N / 2) * (1.0f / TBL_SCALE);
        tbl[k] = __builtin_amdgcn_rcpf(1.0f + __builtin_amdgcn_exp2f(t));
    }

    // stage x = inputs*in_w + in_b (128 values; first 128 threads)
    if (tid < NIN * RPB) {
        int i = tid & (NIN - 1);
        int r = tid >> 5;
        xs[i * RPB + r] = inputs[(base + r) * NIN + i] * in_w[i] + in_b[i];
    }
    // stage initial v (512 values, 1 per thread: this thread's update row q)
    float vold = state[(base + q) * NU + j];
    vs[j * RPB + q] = vold;
    __syncthreads();

    const int slo = SLOC[q], shi = SLOC[q + 1];
    const int rlo = RLOC[q], rhi = RLOC[q + 1];

    // ---- sensory partial sums over this thread's i-range, all 4 rows ----
    float numS[RPB], denS[RPB];
    #pragma unroll
    for (int r = 0; r < RPB; ++r) { numS[r] = 0.0f; denS[r] = 0.0f; }
    if (q < 2) {
        const float4v* pp = spe + slo * NU + j;
        #pragma unroll 2
        for (int i = slo; i < shi; ++i) {
            float4v p = pp[0]; pp += NU;
            float4v xv = *(const float4v*)&xs[i * RPB];
            EVAL_PAIR(p, xv[0], xv[1], numS[0], denS[0], numS[1], denS[1]);
            EVAL_PAIR(p, xv[2], xv[3], numS[2], denS[2], numS[3], denS[3]);
        }
    } else {
        const float4v* pp = spt + slo * NU + j;
        #pragma unroll 2
        for (int i = slo; i < shi; ++i) {
            float4v p = pp[0]; pp += NU;
            float4v xv = *(const float4v*)&xs[i * RPB];
            #pragma unroll
            for (int r = 0; r < RPB; ++r) { EVAL_TBL(p, xv[r], numS[r], denS[r]); }
        }
    }

    // per-unit constants
    const float cm = cm_t[j];
    const float gl = gleak[j];
    const float glvl = gl * vleak[j];
    const float cg = cm + gl;

    // ---- 6 semi-implicit unfolds ----
    for (int u = 0; u < UNFOLDS; ++u) {
        float num[RPB], den[RPB];
        #pragma unroll
        for (int r = 0; r < RPB; ++r) { num[r] = numS[r]; den[r] = denS[r]; }

        if (q < 2) {
            const float4v* pp = rpe + rlo * NU + j;
            #pragma unroll 2
            for (int i = rlo; i < rhi; ++i) {
                float4v p = pp[0]; pp += NU;
                float4v vv = *(const float4v*)&vs[i * RPB];
                EVAL_PAIR(p, vv[0], vv[1], num[0], den[0], num[1], den[1]);
                EVAL_PAIR(p, vv[2], vv[3], num[2], den[2], num[3], den[3]);
            }
        } else {
            const float4v* pp = rpt + rlo * NU + j;
            #pragma unroll 2
            for (int i = rlo; i < rhi; ++i) {
                float4v p = pp[0]; pp += NU;
                float4v vv = *(const float4v*)&vs[i * RPB];
                #pragma unroll
                for (int r = 0; r < RPB; ++r) { EVAL_TBL(p, vv[r], num[r], den[r]); }
            }
        }

        // publish partials (coalesced over j, conflict-free)
        #pragma unroll
        for (int r = 0; r < RPB; ++r) {
            rn[r][q][j] = num[r];
            rd[r][q][j] = den[r];
        }
        __syncthreads();

        // update this thread's row q
        {
            float tn = (rn[q][0][j] + rn[q][1][j]) + (rn[q][2][j] + rn[q][3][j]);
            float td = (rd[q][0][j] + rd[q][1][j]) + (rd[q][2][j] + rd[q][3][j]);
            float vn = (__builtin_fmaf(cm, vold, glvl) + tn)
                       * __builtin_amdgcn_rcpf(cg + td);
            vold = vn;
            vs[j * RPB + q] = vn;
        }
        __syncthreads();
    }

    // ---- epilogue: thread (j,q) writes its row (coalesced over j) ----
    out_v[(base + q) * NU + j] = vold;
    if (j == 0) {
        out_y[base + q] = __builtin_fmaf(vold, out_w[0], out_b[0]);
    }
}

extern "C" void kernel_launch(void* const* d_in, const int* in_sizes, int n_in,
                              void* d_out, int out_size, void* d_ws, size_t ws_size,
                              hipStream_t stream) {
    const float* inputs  = (const float*)d_in[0];
    const float* state   = (const float*)d_in[1];
    const float* smu     = (const float*)d_in[2];
    const float* ssig    = (const float*)d_in[3];
    const float* sW      = (const float*)d_in[4];
    const float* serev   = (const float*)d_in[5];
    const float* rmu     = (const float*)d_in[6];
    const float* rsig    = (const float*)d_in[7];
    const float* rW      = (const float*)d_in[8];
    const float* rerev   = (const float*)d_in[9];
    const float* vleak   = (const float*)d_in[10];
    const float* gleak   = (const float*)d_in[11];
    const float* cm_t    = (const float*)d_in[12];
    const float* in_w    = (const float*)d_in[13];
    const float* in_b    = (const float*)d_in[14];
    const float* out_w   = (const float*)d_in[15];
    const float* out_b   = (const float*)d_in[16];

    const int batch = in_sizes[1] / NU;        // 8192
    float* out_y = (float*)d_out;              // [batch]
    float* out_v = (float*)d_out + batch;      // [batch,128]

    // workspace layout: spe, spt, rpe, rpt  (640 KB total)
    float4v* spe = (float4v*)d_ws;
    float4v* spt = spe + SPN;
    float4v* rpe = spt + SPN;
    float4v* rpt = rpe + RPN;

    hipLaunchKernelGGL(pack_params, dim3((SPN + 255) / 256), dim3(256), 0, stream,
                       smu, ssig, sW, serev, spe, spt, SPN);
    hipLaunchKernelGGL(pack_params, dim3((RPN + 255) / 256), dim3(256), 0, stream,
                       rmu, rsig, rW, rerev, rpe, rpt, RPN);

    dim3 grid(batch / RPB), block(NU * NQ);    // 2048 x 512
    hipLaunchKernelGGL(wormnet_main, grid, block, 0, stream,
                       inputs, state, spe, spt, rpe, rpt,
                       vleak, gleak, cm_t, in_w, in_b, out_w, out_b,
                       out_y, out_v);
}

// Round 10
// 259.857 us; speedup vs baseline: 1.0915x; 1.0255x over previous
//
#include <hip/hip_runtime.h>

#define NIN 32
#define NU  128
#define RPB 8            // batch rows per block
#define NQ  4            // i-range quarters (threads per j)
#define UNFOLDS 6
#define LOG2E 1.44269504088896340736f
#define TBL_N 4096       // sigmoid table entries over t in [-16, 16)
#define TBL_SCALE 128.0f // entries per unit t
#define TBL_OFF 2048.5f  // center offset + 0.5 for round-to-nearest via trunc

typedef float float4v __attribute__((ext_vector_type(4)));
typedef __fp16 half2v __attribute__((ext_vector_type(2)));

#define SPN (NIN * NU)   // 4096 sensory synapses
#define RPN (NU * NU)    // 16384 recurrent synapses

// i-range split per q: q0,q1 -> exp2 method; q2,q3 -> table method (f=0.58).
__device__ __constant__ int RLOC[5] = {0, 27, 54, 91, 128};
__device__ __constant__ int SLOC[5] = {0, 7, 14, 23, 32};

// ---- prologue: pack params in BOTH spaces ----
// exp2 space:  (s2, sm2, We, Wv), t = s2*v + sm2, sigmoid = 1/(1+2^t)
// table space: (axp, bxp, We, Wv), idx = trunc(axp*v + bxp)
__global__ void pack_params(const float* __restrict__ mu,
                            const float* __restrict__ sig,
                            const float* __restrict__ W,
                            const float* __restrict__ erev,
                            float4v* __restrict__ out_e,
                            float4v* __restrict__ out_t, int n) {
    int idx = blockIdx.x * blockDim.x + threadIdx.x;
    if (idx < n) {
        float sg = sig[idx];
        float s2 = -LOG2E * sg;
        float sm2 = -s2 * mu[idx];
        float Wv = W[idx];
        float We = Wv * erev[idx];
        out_e[idx] = (float4v){s2, sm2, We, Wv};
        out_t[idx] = (float4v){TBL_SCALE * s2,
                               __builtin_fmaf(TBL_SCALE, sm2, TBL_OFF), We, Wv};
    }
}

// exp2 pair (rows r0,r1), pair-shared rcp:
#define EVAL_PAIR(p, v0, v1, n0, d0, n1, d1)                                   \
    {                                                                          \
        float e0 = __builtin_amdgcn_exp2f(__builtin_fmaf((p).x, (v0), (p).y)); \
        float e1 = __builtin_amdgcn_exp2f(__builtin_fmaf((p).x, (v1), (p).y)); \
        float a1 = 1.0f + e1;                                                  \
        float P  = __builtin_fmaf(e0, a1, a1);                                 \
        float rq = __builtin_amdgcn_rcpf(P);                                   \
        float s0 = rq * a1;                                                    \
        float s1 = __builtin_fmaf(rq, e0, rq);                                 \
        (n0) = __builtin_fmaf((p).z, s0, (n0));                                \
        (d0) = __builtin_fmaf((p).w, s0, (d0));                                \
        (n1) = __builtin_fmaf((p).z, s1, (n1));                                \
        (d1) = __builtin_fmaf((p).w, s1, (d1));                                \
    }

// table eval: fma (addr) + fmed3 clamp + cvt + gather + 2 accum fma
#define EVAL_TBL(p, v, n_, d_)                                                 \
    {                                                                          \
        float af = __builtin_fmaf((p).x, (v), (p).y);                          \
        af = __builtin_amdgcn_fmed3f(af, 0.0f, (float)(TBL_N - 1));            \
        float s = tbl[(unsigned)af];                                           \
        (n_) = __builtin_fmaf((p).z, s, (n_));                                 \
        (d_) = __builtin_fmaf((p).w, s, (d_));                                 \
    }

// block = 512 threads: j = tid&127 (unit), q = tid>>7 (wave-uniform).
// q selects BOTH the i-range and the method: q0,q1 exact exp2 (42% of evals,
// issue pipe); q2,q3 LDS table (58%, LDS pipe). 8 batch rows per block amortize
// the ~40cyc/i fixed cost over 8 evals; partials published as half2
// (v_cvt_pkrtz) so LDS stays at 37 KB -> 4 blocks/CU, 8 waves/SIMD.
// Thread (j,q) owns v-updates for rows 2q, 2q+1.
__global__ __launch_bounds__(512, 8)
void wormnet_main(const float* __restrict__ inputs,   // [B,32]
                  const float* __restrict__ state,    // [B,128]
                  const float4v* __restrict__ spe, const float4v* __restrict__ spt,
                  const float4v* __restrict__ rpe, const float4v* __restrict__ rpt,
                  const float* __restrict__ vleak,
                  const float* __restrict__ gleak,
                  const float* __restrict__ cm_t,
                  const float* __restrict__ in_w, const float* __restrict__ in_b,
                  const float* __restrict__ out_w, const float* __restrict__ out_b,
                  float* __restrict__ out_y,          // [B]
                  float* __restrict__ out_v)          // [B,128]
{
    __shared__ __align__(16) float tbl[TBL_N];        // sigmoid table   16 KB
    __shared__ __align__(16) float xs[NIN * RPB];     // xs[i*8 + r]      1 KB
    __shared__ __align__(16) float vs[NU * RPB];      // vs[i*8 + r]      4 KB
    __shared__ unsigned prt[RPB][NQ][NU];             // half2(num,den)  16 KB

    const int tid  = threadIdx.x;
    const int j    = tid & (NU - 1);
    const int q    = tid >> 7;            // 0..3, wave-uniform
    const int u0   = q * 2;               // owner rows u0, u0+1
    const int base = blockIdx.x * RPB;

    // build sigmoid table: s(t_k) = 1/(1+2^t), t_k = (k - 2048)/128
    #pragma unroll
    for (int k = tid; k < TBL_N; k += 512) {
        float t = (float)(k - TBL_N / 2) * (1.0f / TBL_SCALE);
        tbl[k] = __builtin_amdgcn_rcpf(1.0f + __builtin_amdgcn_exp2f(t));
    }

    // stage x = inputs*in_w + in_b (256 values; first 256 threads)
    if (tid < NIN * RPB) {
        int i = tid & (NIN - 1);
        int r = tid >> 5;
        xs[i * RPB + r] = inputs[(base + r) * NIN + i] * in_w[i] + in_b[i];
    }
    // stage initial v (1024 values, 2 per thread: owner rows, coalesced in j)
    float vold[2];
    #pragma unroll
    for (int k = 0; k < 2; ++k) {
        vold[k] = state[(base + u0 + k) * NU + j];
        vs[j * RPB + u0 + k] = vold[k];
    }
    __syncthreads();

    const int slo = SLOC[q], shi = SLOC[q + 1];
    const int rlo = RLOC[q], rhi = RLOC[q + 1];

    // ---- sensory partial sums over this thread's i-range, all 8 rows ----
    float numS[RPB], denS[RPB];
    #pragma unroll
    for (int r = 0; r < RPB; ++r) { numS[r] = 0.0f; denS[r] = 0.0f; }
    if (q < 2) {
        const float4v* pp = spe + slo * NU + j;
        for (int i = slo; i < shi; ++i) {
            float4v p = pp[0]; pp += NU;
            float4v xa = *(const float4v*)&xs[i * RPB];
            float4v xb = *(const float4v*)&xs[i * RPB + 4];
            EVAL_PAIR(p, xa[0], xa[1], numS[0], denS[0], numS[1], denS[1]);
            EVAL_PAIR(p, xa[2], xa[3], numS[2], denS[2], numS[3], denS[3]);
            EVAL_PAIR(p, xb[0], xb[1], numS[4], denS[4], numS[5], denS[5]);
            EVAL_PAIR(p, xb[2], xb[3], numS[6], denS[6], numS[7], denS[7]);
        }
    } else {
        const float4v* pp = spt + slo * NU + j;
        for (int i = slo; i < shi; ++i) {
            float4v p = pp[0]; pp += NU;
            float4v xa = *(const float4v*)&xs[i * RPB];
            float4v xb = *(const float4v*)&xs[i * RPB + 4];
            #pragma unroll
            for (int r = 0; r < 4; ++r) { EVAL_TBL(p, xa[r], numS[r], denS[r]); }
            #pragma unroll
            for (int r = 0; r < 4; ++r) { EVAL_TBL(p, xb[r], numS[r + 4], denS[r + 4]); }
        }
    }

    // per-unit constants
    const float cm = cm_t[j];
    const float gl = gleak[j];
    const float glvl = gl * vleak[j];
    const float cg = cm + gl;

    // ---- 6 semi-implicit unfolds ----
    for (int u = 0; u < UNFOLDS; ++u) {
        float num[RPB], den[RPB];
        #pragma unroll
        for (int r = 0; r < RPB; ++r) { num[r] = numS[r]; den[r] = denS[r]; }

        if (q < 2) {
            const float4v* pp = rpe + rlo * NU + j;
            for (int i = rlo; i < rhi; ++i) {
                float4v p = pp[0]; pp += NU;
                float4v va = *(const float4v*)&vs[i * RPB];
                float4v vb = *(const float4v*)&vs[i * RPB + 4];
                EVAL_PAIR(p, va[0], va[1], num[0], den[0], num[1], den[1]);
                EVAL_PAIR(p, va[2], va[3], num[2], den[2], num[3], den[3]);
                EVAL_PAIR(p, vb[0], vb[1], num[4], den[4], num[5], den[5]);
                EVAL_PAIR(p, vb[2], vb[3], num[6], den[6], num[7], den[7]);
            }
        } else {
            const float4v* pp = rpt + rlo * NU + j;
            for (int i = rlo; i < rhi; ++i) {
                float4v p = pp[0]; pp += NU;
                float4v va = *(const float4v*)&vs[i * RPB];
                float4v vb = *(const float4v*)&vs[i * RPB + 4];
                #pragma unroll
                for (int r = 0; r < 4; ++r) { EVAL_TBL(p, va[r], num[r], den[r]); }
                #pragma unroll
                for (int r = 0; r < 4; ++r) { EVAL_TBL(p, vb[r], num[r + 4], den[r + 4]); }
            }
        }

        // publish partials as packed half2 (coalesced over j, conflict-free)
        #pragma unroll
        for (int r = 0; r < RPB; ++r) {
            half2v pk = __builtin_amdgcn_cvt_pkrtz(num[r], den[r]);
            prt[r][q][j] = __builtin_bit_cast(unsigned, pk);
        }
        __syncthreads();

        // update this thread's owner rows u0, u0+1
        #pragma unroll
        for (int k = 0; k < 2; ++k) {
            const int r = u0 + k;
            float tn = 0.0f, td = 0.0f;
            #pragma unroll
            for (int qq = 0; qq < NQ; ++qq) {
                half2v h = __builtin_bit_cast(half2v, prt[r][qq][j]);
                tn += (float)h[0];
                td += (float)h[1];
            }
            float vn = (__builtin_fmaf(cm, vold[k], glvl) + tn)
                       * __builtin_amdgcn_rcpf(cg + td);
            vold[k] = vn;
            vs[j * RPB + r] = vn;
        }
        __syncthreads();
    }

    // ---- epilogue: thread (j,q) writes its 2 rows (coalesced over j) ----
    #pragma unroll
    for (int k = 0; k < 2; ++k) {
        out_v[(base + u0 + k) * NU + j] = vold[k];
    }
    if (j == 0) {
        const float ow = out_w[0], ob = out_b[0];
        #pragma unroll
        for (int k = 0; k < 2; ++k) {
            out_y[base + u0 + k] = __builtin_fmaf(vold[k], ow, ob);
        }
    }
}

extern "C" void kernel_launch(void* const* d_in, const int* in_sizes, int n_in,
                              void* d_out, int out_size, void* d_ws, size_t ws_size,
                              hipStream_t stream) {
    const float* inputs  = (const float*)d_in[0];
    const float* state   = (const float*)d_in[1];
    const float* smu     = (const float*)d_in[2];
    const float* ssig    = (const float*)d_in[3];
    const float* sW      = (const float*)d_in[4];
    const float* serev   = (const float*)d_in[5];
    const float* rmu     = (const float*)d_in[6];
    const float* rsig    = (const float*)d_in[7];
    const float* rW      = (const float*)d_in[8];
    const float* rerev   = (const float*)d_in[9];
    const float* vleak   = (const float*)d_in[10];
    const float* gleak   = (const float*)d_in[11];
    const float* cm_t    = (const float*)d_in[12];
    const float* in_w    = (const float*)d_in[13];
    const float* in_b    = (const float*)d_in[14];
    const float* out_w   = (const float*)d_in[15];
    const float* out_b   = (const float*)d_in[16];

    const int batch = in_sizes[1] / NU;        // 8192
    float* out_y = (float*)d_out;              // [batch]
    float* out_v = (float*)d_out + batch;      // [batch,128]

    // workspace layout: spe, spt, rpe, rpt  (640 KB total)
    float4v* spe = (float4v*)d_ws;
    float4v* spt = spe + SPN;
    float4v* rpe = spt + SPN;
    float4v* rpt = rpe + RPN;

    hipLaunchKernelGGL(pack_params, dim3((SPN + 255) / 256), dim3(256), 0, stream,
                       smu, ssig, sW, serev, spe, spt, SPN);
    hipLaunchKernelGGL(pack_params, dim3((RPN + 255) / 256), dim3(256), 0, stream,
                       rmu, rsig, rW, rerev, rpe, rpt, RPN);

    dim3 grid(batch / RPB), block(NU * NQ);    // 1024 x 512
    hipLaunchKernelGGL(wormnet_main, grid, block, 0, stream,
                       inputs, state, spe, spt, rpe, rpt,
                       vleak, gleak, cm_t, in_w, in_b, out_w, out_b,
                       out_y, out_v);
}

// Round 11
// 251.160 us; speedup vs baseline: 1.1293x; 1.0346x over previous
//
#include <hip/hip_runtime.h>

#define NIN 32
#define NU  128
#define RPB 8            // batch rows per block
#define NQ  4            // i-range quarters (threads per j)
#define UNFOLDS 6
#define LOG2E 1.44269504088896340736f
#define TBL_N 4096       // sigmoid table entries over t in [-16, 16)
#define TBL_SCALE 128.0f // entries per unit t
#define TBL_OFF 2048.5f  // center offset + 0.5 for round-to-nearest via trunc

typedef float float4v __attribute__((ext_vector_type(4)));
typedef __fp16 half2v __attribute__((ext_vector_type(2)));

#define SPN (NIN * NU)   // 4096 sensory synapses
#define RPN (NU * NU)    // 16384 recurrent synapses

// i-range split per q: q0,q1 -> exp2 method; q2,q3 -> table method (f=0.58).
__device__ __constant__ int RLOC[5] = {0, 27, 54, 91, 128};
__device__ __constant__ int SLOC[5] = {0, 7, 14, 23, 32};

// ---- prologue: pack params in BOTH spaces ----
__global__ void pack_params(const float* __restrict__ mu,
                            const float* __restrict__ sig,
                            const float* __restrict__ W,
                            const float* __restrict__ erev,
                            float4v* __restrict__ out_e,
                            float4v* __restrict__ out_t, int n) {
    int idx = blockIdx.x * blockDim.x + threadIdx.x;
    if (idx < n) {
        float sg = sig[idx];
        float s2 = -LOG2E * sg;
        float sm2 = -s2 * mu[idx];
        float Wv = W[idx];
        float We = Wv * erev[idx];
        out_e[idx] = (float4v){s2, sm2, We, Wv};
        out_t[idx] = (float4v){TBL_SCALE * s2,
                               __builtin_fmaf(TBL_SCALE, sm2, TBL_OFF), We, Wv};
    }
}

// exp2 pair (rows r0,r1), pair-shared rcp:
#define EVAL_PAIR(p, v0, v1, n0, d0, n1, d1)                                   \
    {                                                                          \
        float e0 = __builtin_amdgcn_exp2f(__builtin_fmaf((p).x, (v0), (p).y)); \
        float e1 = __builtin_amdgcn_exp2f(__builtin_fmaf((p).x, (v1), (p).y)); \
        float a1 = 1.0f + e1;                                                  \
        float P  = __builtin_fmaf(e0, a1, a1);                                 \
        float rq = __builtin_amdgcn_rcpf(P);                                   \
        float s0 = rq * a1;                                                    \
        float s1 = __builtin_fmaf(rq, e0, rq);                                 \
        (n0) = __builtin_fmaf((p).z, s0, (n0));                                \
        (d0) = __builtin_fmaf((p).w, s0, (d0));                                \
        (n1) = __builtin_fmaf((p).z, s1, (n1));                                \
        (d1) = __builtin_fmaf((p).w, s1, (d1));                                \
    }

// table eval: fma (addr) + fmed3 clamp + cvt + gather + 2 accum fma
#define EVAL_TBL(p, v, n_, d_)                                                 \
    {                                                                          \
        float af = __builtin_fmaf((p).x, (v), (p).y);                          \
        af = __builtin_amdgcn_fmed3f(af, 0.0f, (float)(TBL_N - 1));            \
        float s = tbl[(unsigned)af];                                           \
        (n_) = __builtin_fmaf((p).z, s, (n_));                                 \
        (d_) = __builtin_fmaf((p).w, s, (d_));                                 \
    }

// block = 512: j = tid&127, q = tid>>7 (wave-uniform; selects i-range+method).
// Sensory sums computed ONCE, reduced to wsum (half2, 4KB LDS) so no sensory
// accumulators stay live in registers across the unfold loop (R10's spill
// source). xs overlays prt (dead before first publish) -> LDS = 40960 B
// exactly = 4 blocks/CU, 8 waves/SIMD. Thread (j,q) owns rows 2q, 2q+1.
__global__ __launch_bounds__(512, 8)
void wormnet_main(const float* __restrict__ inputs,   // [B,32]
                  const float* __restrict__ state,    // [B,128]
                  const float4v* __restrict__ spe, const float4v* __restrict__ spt,
                  const float4v* __restrict__ rpe, const float4v* __restrict__ rpt,
                  const float* __restrict__ vleak,
                  const float* __restrict__ gleak,
                  const float* __restrict__ cm_t,
                  const float* __restrict__ in_w, const float* __restrict__ in_b,
                  const float* __restrict__ out_w, const float* __restrict__ out_b,
                  float* __restrict__ out_y,          // [B]
                  float* __restrict__ out_v)          // [B,128]
{
    __shared__ __align__(16) float tbl[TBL_N];        // 16 KB
    __shared__ __align__(16) float vs[NU * RPB];      //  4 KB  vs[i*8 + r]
    __shared__ __align__(16) union {
        float xs[NIN * RPB];                          //  (1 KB used)
        unsigned prt[RPB][NQ][NU];                    // 16 KB  half2(num,den)
    } sm;
    __shared__ unsigned wsum[RPB][NU];                //  4 KB  half2 sensory

    const int tid  = threadIdx.x;
    const int j    = tid & (NU - 1);
    const int q    = tid >> 7;            // 0..3, wave-uniform
    const int u0   = q * 2;               // owner rows u0, u0+1
    const int base = blockIdx.x * RPB;

    // build sigmoid table: s(t_k) = 1/(1+2^t), t_k = (k - 2048)/128
    #pragma unroll
    for (int k = tid; k < TBL_N; k += 512) {
        float t = (float)(k - TBL_N / 2) * (1.0f / TBL_SCALE);
        tbl[k] = __builtin_amdgcn_rcpf(1.0f + __builtin_amdgcn_exp2f(t));
    }

    // stage x = inputs*in_w + in_b (256 values; first 256 threads)
    if (tid < NIN * RPB) {
        int i = tid & (NIN - 1);
        int r = tid >> 5;
        sm.xs[i * RPB + r] = inputs[(base + r) * NIN + i] * in_w[i] + in_b[i];
    }
    // stage initial v (1024 values, 2 per thread: owner rows, coalesced in j)
    float vold[2];
    #pragma unroll
    for (int k = 0; k < 2; ++k) {
        vold[k] = state[(base + u0 + k) * NU + j];
        vs[j * RPB + u0 + k] = vold[k];
    }
    __syncthreads();

    const int slo = SLOC[q], shi = SLOC[q + 1];
    const int rlo = RLOC[q], rhi = RLOC[q + 1];

    // ---- sensory phase: partials -> prt -> reduce to wsum (once) ----
    {
        float numS[RPB], denS[RPB];
        #pragma unroll
        for (int r = 0; r < RPB; ++r) { numS[r] = 0.0f; denS[r] = 0.0f; }
        if (q < 2) {
            const float4v* pp = spe + slo * NU + j;
            for (int i = slo; i < shi; ++i) {
                float4v p = pp[0]; pp += NU;
                float4v xa = *(const float4v*)&sm.xs[i * RPB];
                float4v xb = *(const float4v*)&sm.xs[i * RPB + 4];
                EVAL_PAIR(p, xa[0], xa[1], numS[0], denS[0], numS[1], denS[1]);
                EVAL_PAIR(p, xa[2], xa[3], numS[2], denS[2], numS[3], denS[3]);
                EVAL_PAIR(p, xb[0], xb[1], numS[4], denS[4], numS[5], denS[5]);
                EVAL_PAIR(p, xb[2], xb[3], numS[6], denS[6], numS[7], denS[7]);
            }
        } else {
            const float4v* pp = spt + slo * NU + j;
            for (int i = slo; i < shi; ++i) {
                float4v p = pp[0]; pp += NU;
                float4v xa = *(const float4v*)&sm.xs[i * RPB];
                float4v xb = *(const float4v*)&sm.xs[i * RPB + 4];
                #pragma unroll
                for (int r = 0; r < 4; ++r) { EVAL_TBL(p, xa[r], numS[r], denS[r]); }
                #pragma unroll
                for (int r = 0; r < 4; ++r) { EVAL_TBL(p, xb[r], numS[r + 4], denS[r + 4]); }
            }
        }
        __syncthreads();   // all xs reads done before prt overwrite
        #pragma unroll
        for (int r = 0; r < RPB; ++r) {
            half2v pk = __builtin_amdgcn_cvt_pkrtz(numS[r], denS[r]);
            sm.prt[r][q][j] = __builtin_bit_cast(unsigned, pk);
        }
        __syncthreads();
        // each thread reduces 2 (r,j') pairs into wsum
        #pragma unroll
        for (int k = 0; k < 2; ++k) {
            int m = 2 * tid + k;
            int rr = m >> 7, jj = m & (NU - 1);
            float tn = 0.0f, td = 0.0f;
            #pragma unroll
            for (int qq = 0; qq < NQ; ++qq) {
                half2v h = __builtin_bit_cast(half2v, sm.prt[rr][qq][jj]);
                tn += (float)h[0];
                td += (float)h[1];
            }
            wsum[rr][jj] = __builtin_bit_cast(unsigned,
                               __builtin_amdgcn_cvt_pkrtz(tn, td));
        }
        __syncthreads();   // wsum ready; prt reads done before unfold publish
    }

    // per-unit constants
    const float cm = cm_t[j];
    const float gl = gleak[j];
    const float glvl = gl * vleak[j];
    const float cg = cm + gl;

    // ---- 6 semi-implicit unfolds ----
    for (int u = 0; u < UNFOLDS; ++u) {
        float num[RPB], den[RPB];
        #pragma unroll
        for (int r = 0; r < RPB; ++r) { num[r] = 0.0f; den[r] = 0.0f; }

        if (q < 2) {
            const float4v* pp = rpe + rlo * NU + j;
            for (int i = rlo; i < rhi; ++i) {
                float4v p = pp[0]; pp += NU;
                float4v va = *(const float4v*)&vs[i * RPB];
                float4v vb = *(const float4v*)&vs[i * RPB + 4];
                EVAL_PAIR(p, va[0], va[1], num[0], den[0], num[1], den[1]);
                EVAL_PAIR(p, va[2], va[3], num[2], den[2], num[3], den[3]);
                EVAL_PAIR(p, vb[0], vb[1], num[4], den[4], num[5], den[5]);
                EVAL_PAIR(p, vb[2], vb[3], num[6], den[6], num[7], den[7]);
            }
        } else {
            const float4v* pp = rpt + rlo * NU + j;
            for (int i = rlo; i < rhi; ++i) {
                float4v p = pp[0]; pp += NU;
                float4v va = *(const float4v*)&vs[i * RPB];
                float4v vb = *(const float4v*)&vs[i * RPB + 4];
                #pragma unroll
                for (int r = 0; r < 4; ++r) { EVAL_TBL(p, va[r], num[r], den[r]); }
                #pragma unroll
                for (int r = 0; r < 4; ++r) { EVAL_TBL(p, vb[r], num[r + 4], den[r + 4]); }
            }
        }

        // publish partials as packed half2 (coalesced over j, conflict-free)
        #pragma unroll
        for (int r = 0; r < RPB; ++r) {
            half2v pk = __builtin_amdgcn_cvt_pkrtz(num[r], den[r]);
            sm.prt[r][q][j] = __builtin_bit_cast(unsigned, pk);
        }
        __syncthreads();

        // update this thread's owner rows u0, u0+1 (sensory from wsum)
        #pragma unroll
        for (int k = 0; k < 2; ++k) {
            const int r = u0 + k;
            half2v hs = __builtin_bit_cast(half2v, wsum[r][j]);
            float tn = (float)hs[0], td = (float)hs[1];
            #pragma unroll
            for (int qq = 0; qq < NQ; ++qq) {
                half2v h = __builtin_bit_cast(half2v, sm.prt[r][qq][j]);
                tn += (float)h[0];
                td += (float)h[1];
            }
            float vn = (__builtin_fmaf(cm, vold[k], glvl) + tn)
                       * __builtin_amdgcn_rcpf(cg + td);
            vold[k] = vn;
            vs[j * RPB + r] = vn;
        }
        __syncthreads();
    }

    // ---- epilogue: thread (j,q) writes its 2 rows (coalesced over j) ----
    #pragma unroll
    for (int k = 0; k < 2; ++k) {
        out_v[(base + u0 + k) * NU + j] = vold[k];
    }
    if (j == 0) {
        const float ow = out_w[0], ob = out_b[0];
        #pragma unroll
        for (int k = 0; k < 2; ++k) {
            out_y[base + u0 + k] = __builtin_fmaf(vold[k], ow, ob);
        }
    }
}

extern "C" void kernel_launch(void* const* d_in, const int* in_sizes, int n_in,
                              void* d_out, int out_size, void* d_ws, size_t ws_size,
                              hipStream_t stream) {
    const float* inputs  = (const float*)d_in[0];
    const float* state   = (const float*)d_in[1];
    const float* smu     = (const float*)d_in[2];
    const float* ssig    = (const float*)d_in[3];
    const float* sW      = (const float*)d_in[4];
    const float* serev   = (const float*)d_in[5];
    const float* rmu     = (const float*)d_in[6];
    const float* rsig    = (const float*)d_in[7];
    const float* rW      = (const float*)d_in[8];
    const float* rerev   = (const float*)d_in[9];
    const float* vleak   = (const float*)d_in[10];
    const float* gleak   = (const float*)d_in[11];
    const float* cm_t    = (const float*)d_in[12];
    const float* in_w    = (const float*)d_in[13];
    const float* in_b    = (const float*)d_in[14];
    const float* out_w   = (const float*)d_in[15];
    const float* out_b   = (const float*)d_in[16];

    const int batch = in_sizes[1] / NU;        // 8192
    float* out_y = (float*)d_out;              // [batch]
    float* out_v = (float*)d_out + batch;      // [batch,128]

    // workspace layout: spe, spt, rpe, rpt  (640 KB total)
    float4v* spe = (float4v*)d_ws;
    float4v* spt = spe + SPN;
    float4v* rpe = spt + SPN;
    float4v* rpt = rpe + RPN;

    hipLaunchKernelGGL(pack_params, dim3((SPN + 255) / 256), dim3(256), 0, stream,
                       smu, ssig, sW, serev, spe, spt, SPN);
    hipLaunchKernelGGL(pack_params, dim3((RPN + 255) / 256), dim3(256), 0, stream,
                       rmu, rsig, rW, rerev, rpe, rpt, RPN);

    dim3 grid(batch / RPB), block(NU * NQ);    // 1024 x 512
    hipLaunchKernelGGL(wormnet_main, grid, block, 0, stream,
                       inputs, state, spe, spt, rpe, rpt,
                       vleak, gleak, cm_t, in_w, in_b, out_w, out_b,
                       out_y, out_v);
}